// Round 1
// baseline (479.409 us; speedup 1.0000x reference)
//
#include <hip/hip_runtime.h>

typedef __attribute__((ext_vector_type(8))) _Float16 half8;
typedef __attribute__((ext_vector_type(4))) float f32x4;

#define NF       1024
#define BM       64
#define NTHREADS 512      // 8 waves
#define NSLABS   8        // K slabs of 128
#define SLABK    128
#define WCOPY0   2048
#define WCOPYS   2040
#define WTOT     (WCOPY0 + 7 * WCOPYS)   // 16328 fp16 elements

// out[b,i] = mm*x + mm + x,  mm[b,i] = sum_j x[b,j] * w[(j-i) mod 1024]
// MFMA mapping: m->token row, n->output col i, k->j.
// B[k][n] = wext[1024 + k - i], wext[u] = w[u & 1023].
// 8 shifted LDS copies of wext give every lane a 16B-aligned ds_read_b128.
__global__ __launch_bounds__(NTHREADS, 2)
void circ_kernel(const float* __restrict__ x, const float* __restrict__ wsrc,
                 float* __restrict__ out) {
    // A tile: [128 windows of k>>3][64 rows][8 k-elems], fp16: 128 KiB
    __shared__ __align__(16) _Float16 lds_A[128 * 64 * 8];
    __shared__ __align__(16) _Float16 lds_W[WTOT];            // ~31.9 KiB

    const int tid  = threadIdx.x;
    const int bm   = blockIdx.x;        // 64-row tile index
    const int lane = tid & 63;
    const int wv   = tid >> 6;          // wave 0..7 -> cols [wv*128, +128)
    const int l15  = lane & 15;         // MFMA m (A) / n (B,C) index
    const int quad = lane >> 4;         // MFMA k-block (A,B) / row-block (C)

    // ---- stage 8 shifted copies of circulant weights (fp16) ----
    for (int idx = tid; idx < WTOT; idx += NTHREADS) {
        int s, t;
        if (idx < WCOPY0) { s = 0; t = idx; }
        else { int r = idx - WCOPY0; s = 1 + r / WCOPYS; t = r - (s - 1) * WCOPYS; }
        lds_W[idx] = (_Float16)wsrc[(t + s) & (NF - 1)];
    }

    // ---- A staging: thread -> (row sr, 16-col chunk skc) ----
    const int sr  = tid >> 3;           // 0..63
    const int skc = tid & 7;            // 0..7
    const float* xrow = x + ((size_t)(bm * BM + sr) << 10) + skc * 16;

    f32x4 st[4];
    #pragma unroll
    for (int c = 0; c < 4; ++c) st[c] = *(const f32x4*)(xrow + c * 4);

    auto write_slab = [&](int slab) {
        half8 h0, h1;
        #pragma unroll
        for (int e = 0; e < 8; ++e) h0[e] = (_Float16)st[e >> 2][e & 3];
        #pragma unroll
        for (int e = 0; e < 8; ++e) h1[e] = (_Float16)st[2 + (e >> 2)][e & 3];
        int w0 = slab * 16 + skc * 2;
        *(half8*)&lds_A[(w0 * 64 + sr) * 8]       = h0;
        *(half8*)&lds_A[((w0 + 1) * 64 + sr) * 8] = h1;
    };
    write_slab(0);

    // ---- per-lane B base offsets (one per n-frag f); k0*1 added per kstep ----
    int bbase[8];
    #pragma unroll
    for (int f = 0; f < 8; ++f) {
        int icol = wv * 128 + f * 16 + l15;
        int o0   = 1024 + 8 * quad - icol;      // window start at k0=0
        int s    = o0 & 7;                      // invariant across ksteps
        int t0   = o0 - s;                      // 8-elem aligned
        int offs = (s == 0) ? 0 : (WCOPY0 + (s - 1) * WCOPYS);
        bbase[f] = offs + t0;
    }

    f32x4 acc[4][8];
    #pragma unroll
    for (int a = 0; a < 4; ++a)
        #pragma unroll
        for (int b = 0; b < 8; ++b)
            acc[a][b] = (f32x4){0.f, 0.f, 0.f, 0.f};

    __syncthreads();

    for (int slab = 0; slab < NSLABS; ++slab) {
        if (slab + 1 < NSLABS) {                 // prefetch next slab -> regs
            const float* xs = xrow + (slab + 1) * SLABK;
            #pragma unroll
            for (int c = 0; c < 4; ++c) st[c] = *(const f32x4*)(xs + c * 4);
        }
        #pragma unroll
        for (int ks = 0; ks < 4; ++ks) {
            const int k0 = slab * SLABK + ks * 32;
            half8 bfr[8];
            #pragma unroll
            for (int f = 0; f < 8; ++f)
                bfr[f] = *(const half8*)&lds_W[bbase[f] + k0];
            half8 afr[4];
            #pragma unroll
            for (int mf = 0; mf < 4; ++mf)
                afr[mf] = *(const half8*)&lds_A[(((k0 >> 3) + quad) * 64 + mf * 16 + l15) * 8];
            #pragma unroll
            for (int mf = 0; mf < 4; ++mf)
                #pragma unroll
                for (int f = 0; f < 8; ++f)
                    acc[mf][f] = __builtin_amdgcn_mfma_f32_16x16x32_f16(
                        afr[mf], bfr[f], acc[mf][f], 0, 0, 0);
        }
        if (slab + 1 < NSLABS) write_slab(slab + 1);  // cvt + ds_write after compute
        __syncthreads();
    }

    // ---- epilogue: out = mm*x + mm + x ; x re-read from resident LDS A ----
    #pragma unroll
    for (int mf = 0; mf < 4; ++mf) {
        #pragma unroll
        for (int f = 0; f < 8; ++f) {
            int icol = wv * 128 + f * 16 + l15;
            f32x4 v = acc[mf][f];
            #pragma unroll
            for (int reg = 0; reg < 4; ++reg) {
                int m = mf * 16 + quad * 4 + reg;    // C/D row = quad*4+reg
                float xf = (float)lds_A[((icol >> 3) * 64 + m) * 8 + (icol & 7)];
                float mm = v[reg];
                out[((size_t)(bm * BM + m) << 10) + icol] = mm * xf + mm + xf;
            }
        }
    }
}

extern "C" void kernel_launch(void* const* d_in, const int* in_sizes, int n_in,
                              void* d_out, int out_size, void* d_ws, size_t ws_size,
                              hipStream_t stream) {
    const float* x = (const float*)d_in[0];
    const float* w = (const float*)d_in[1];
    float* o       = (float*)d_out;
    circ_kernel<<<dim3(65536 / BM), dim3(NTHREADS), 0, stream>>>(x, w, o);
}